// Round 6
// baseline (441.927 us; speedup 1.0000x reference)
//
#include <hip/hip_runtime.h>

typedef unsigned short u16;
typedef unsigned int u32;
typedef __attribute__((ext_vector_type(8))) short short8;
typedef __attribute__((ext_vector_type(4))) float f32x4;

// ---------------- helpers ----------------
__device__ __forceinline__ u16 f2bf(float f) {
    unsigned int u = __float_as_uint(f);
    u += 0x7fffu + ((u >> 16) & 1u);   // round-to-nearest-even
    return (u16)(u >> 16);
}

// pack two f32 -> two truncated bf16 in one u32: low16 = hi16(a), high16 = hi16(b)
__device__ __forceinline__ u32 pack_trunc(float a, float b) {
    return __builtin_amdgcn_perm(__float_as_uint(b), __float_as_uint(a), 0x07060302u);
}

// ---------------- batched QKV GEMM v2 ----------------
// Reads fp32 X and W directly (no pre-cast), converts to bf16 during LDS
// staging (padded rows -> conflict-free frag reads). BK=64: 16 K-iters,
// 32 MFMA per barrier-pair. XCD-swizzled 1-D grid (1536 blocks).
#define AST 72   // LDS row stride (u16) = 64 + 8 pad

__global__ __launch_bounds__(256, 3) void gemm_qkv(const float* __restrict__ Xk,
                                                   const float* __restrict__ Xq,
                                                   const float* __restrict__ Xv,
                                                   const float* __restrict__ Wk,
                                                   const float* __restrict__ Wq,
                                                   const float* __restrict__ Wv,
                                                   const float* __restrict__ bK,
                                                   const float* __restrict__ bQ,
                                                   const float* __restrict__ bV,
                                                   u16* __restrict__ Kbh,
                                                   u16* __restrict__ Qbh,
                                                   u16* __restrict__ Vtg,
                                                   float kscale) {
    __shared__ u16 sA[128 * AST];
    __shared__ u16 sB[128 * AST];
    const int f = blockIdx.x;
    const int z = f >> 9;
    const int r9 = f & 511;
    const int i_idx = (r9 & 7) | (((r9 >> 6) & 7) << 3);
    const int j_idx = (r9 >> 3) & 7;

    const float* X = z == 0 ? Xk : (z == 1 ? Xq : Xv);
    const float* W = z == 0 ? Wk : (z == 1 ? Wq : Wv);
    const float* bias = z == 0 ? bK : (z == 1 ? bQ : bV);
    u16* out = z == 0 ? Kbh : (z == 1 ? Qbh : Vtg);
    const float scale = z == 0 ? kscale : 1.0f;

    const int tid  = threadIdx.x;
    const int wave = tid >> 6, lane = tid & 63;
    const int quad = lane >> 4, l16 = lane & 15;
    const int wm = wave & 1, wn = wave >> 1;
    const int i0 = i_idx * 128, j0 = j_idx * 128;
    const int srow = tid >> 3, sseg = tid & 7;   // 32 rows x 8 col-groups per pass

    f32x4 acc[4][4];
    #pragma unroll
    for (int mt = 0; mt < 4; mt++)
        #pragma unroll
        for (int nt = 0; nt < 4; nt++) acc[mt][nt] = (f32x4){0.f, 0.f, 0.f, 0.f};

    for (int kk = 0; kk < 1024; kk += 64) {
        __syncthreads();
        // stage A (X fp32 -> bf16) and B (W fp32 -> bf16), 4 passes each
        #pragma unroll
        for (int p = 0; p < 4; p++) {
            int r = p * 32 + srow;
            const float* g = X + (size_t)(i0 + r) * 1024 + kk + sseg * 8;
            float4 v0 = *(const float4*)g;
            float4 v1 = *(const float4*)(g + 4);
            uint4 pk = { pack_trunc(v0.x, v0.y), pack_trunc(v0.z, v0.w),
                         pack_trunc(v1.x, v1.y), pack_trunc(v1.z, v1.w) };
            *(uint4*)&sA[r * AST + sseg * 8] = pk;
        }
        #pragma unroll
        for (int p = 0; p < 4; p++) {
            int r = p * 32 + srow;
            const float* g = W + (size_t)(j0 + r) * 1024 + kk + sseg * 8;
            float4 v0 = *(const float4*)g;
            float4 v1 = *(const float4*)(g + 4);
            uint4 pk = { pack_trunc(v0.x, v0.y), pack_trunc(v0.z, v0.w),
                         pack_trunc(v1.x, v1.y), pack_trunc(v1.z, v1.w) };
            *(uint4*)&sB[r * AST + sseg * 8] = pk;
        }
        __syncthreads();
        #pragma unroll
        for (int ks = 0; ks < 2; ks++) {
            short8 af[4], bf[4];
            #pragma unroll
            for (int mt = 0; mt < 4; mt++)
                af[mt] = *(const short8*)&sA[(wm * 64 + mt * 16 + l16) * AST + ks * 32 + quad * 8];
            #pragma unroll
            for (int nt = 0; nt < 4; nt++)
                bf[nt] = *(const short8*)&sB[(wn * 64 + nt * 16 + l16) * AST + ks * 32 + quad * 8];
            #pragma unroll
            for (int mt = 0; mt < 4; mt++)
                #pragma unroll
                for (int nt = 0; nt < 4; nt++)
                    acc[mt][nt] = __builtin_amdgcn_mfma_f32_16x16x32_bf16(af[mt], bf[nt], acc[mt][nt], 0, 0, 0);
        }
    }

    #pragma unroll
    for (int mt = 0; mt < 4; mt++) {
        #pragma unroll
        for (int nt = 0; nt < 4; nt++) {
            int j = j0 + wn * 64 + nt * 16 + l16;
            float bj = bias[j];
            #pragma unroll
            for (int r = 0; r < 4; r++) {
                int i = i0 + wm * 64 + mt * 16 + quad * 4 + r;
                float v = (acc[mt][nt][r] + bj) * scale;
                int b = i >> 11, t = i & 2047;
                int h = j >> 6,  dd = j & 63;
                size_t idx;
                if (z == 2) idx = (((size_t)(b * 16 + h)) * 64 + dd) * 2048 + t;
                else        idx = (((size_t)(b * 16 + h)) * 2048 + t) * 64 + dd;
                out[idx] = f2bf(v);
            }
        }
    }
}

// ---------------- output GEMM v2: 128x64 tile, BK=32, padded LDS ----------------
// A = ctx (bf16) staged via VGPR; B = Wo (fp32) converted in staging.
#define OST 40   // LDS row stride (u16) = 32 + 8 pad

__global__ __launch_bounds__(256) void gemm_out(const u16* __restrict__ X,
                                                const float* __restrict__ W,
                                                const float* __restrict__ bias,
                                                float* __restrict__ out) {
    __shared__ u16 sA[128 * OST];
    __shared__ u16 sB[64 * OST];
    const int f = blockIdx.x;
    const int j_idx = (f >> 3) & 15;
    const int i_idx = (f & 7) | ((f >> 7) << 3);
    const int tid  = threadIdx.x;
    const int wave = tid >> 6, lane = tid & 63;
    const int quad = lane >> 4, l16 = lane & 15;
    const int wm = wave & 1, wn = wave >> 1;
    const int i0 = i_idx * 128, j0 = j_idx * 64;
    const int arow = tid >> 2, aseg = tid & 3;   // A: 64 rows x 4 col-groups/pass

    f32x4 acc[4][2];
    #pragma unroll
    for (int mt = 0; mt < 4; mt++) {
        acc[mt][0] = (f32x4){0.f, 0.f, 0.f, 0.f};
        acc[mt][1] = (f32x4){0.f, 0.f, 0.f, 0.f};
    }

    for (int kk = 0; kk < 1024; kk += 32) {
        __syncthreads();
        // stage A: bf16 pass-through, 2 passes of 64 rows
        #pragma unroll
        for (int p = 0; p < 2; p++) {
            int r = p * 64 + arow;
            uint4 v = *(const uint4*)(X + (size_t)(i0 + r) * 1024 + kk + aseg * 8);
            *(uint4*)&sA[r * OST + aseg * 8] = v;
        }
        // stage B: Wo fp32 -> bf16, one pass (64 rows x 4 groups of 8 floats)
        {
            const float* g = W + (size_t)(j0 + arow) * 1024 + kk + aseg * 8;
            float4 v0 = *(const float4*)g;
            float4 v1 = *(const float4*)(g + 4);
            uint4 pk = { pack_trunc(v0.x, v0.y), pack_trunc(v0.z, v0.w),
                         pack_trunc(v1.x, v1.y), pack_trunc(v1.z, v1.w) };
            *(uint4*)&sB[arow * OST + aseg * 8] = pk;
        }
        __syncthreads();
        short8 af[4], bf[2];
        #pragma unroll
        for (int mt = 0; mt < 4; mt++)
            af[mt] = *(const short8*)&sA[(wm * 64 + mt * 16 + l16) * OST + quad * 8];
        #pragma unroll
        for (int nt = 0; nt < 2; nt++)
            bf[nt] = *(const short8*)&sB[(wn * 32 + nt * 16 + l16) * OST + quad * 8];
        #pragma unroll
        for (int mt = 0; mt < 4; mt++)
            #pragma unroll
            for (int nt = 0; nt < 2; nt++)
                acc[mt][nt] = __builtin_amdgcn_mfma_f32_16x16x32_bf16(af[mt], bf[nt], acc[mt][nt], 0, 0, 0);
    }

    #pragma unroll
    for (int mt = 0; mt < 4; mt++) {
        #pragma unroll
        for (int nt = 0; nt < 2; nt++) {
            int j = j0 + wn * 32 + nt * 16 + l16;
            float bj = bias[j];
            #pragma unroll
            for (int r = 0; r < 4; r++) {
                int i = i0 + wm * 64 + mt * 16 + quad * 4 + r;
                out[(size_t)i * 1024 + j] = acc[mt][nt][r] + bj;
            }
        }
    }
}

// ---------------- flash attention (unchanged from round 5) ----------------
#define QST 72   // LDS row stride in u16

__global__ __launch_bounds__(256, 2) void attn_kernel(const u16* __restrict__ Kbh,
                                                      const u16* __restrict__ Qbh,
                                                      const u16* __restrict__ Vtg,
                                                      u16* __restrict__ ctx) {
    __shared__ u16 sQ[64 * QST];             // [s_local][dk]
    __shared__ u16 sVt[64 * QST];            // [dk][s_local]
    __shared__ u16 sP[4 * 2 * 16 * QST];     // [wave][buf][t16][s64]
    const int f = blockIdx.x;
    const int bh = (f & 7) | ((f >> 6) << 3);
    const int tx = (f >> 3) & 7;
    const int tid  = threadIdx.x;
    const int wave = tid >> 6, lane = tid & 63;
    const int quad = lane >> 4, l16 = lane & 15;
    const int t0 = tx * 256;
    const int tw = t0 + wave * 64;
    const size_t base = (size_t)bh * 2048 * 64;

    short8 bk[4][2];
    #pragma unroll
    for (int g = 0; g < 4; g++) {
        const u16* kr = Kbh + base + (size_t)(tw + g * 16 + l16) * 64 + quad * 8;
        bk[g][0] = *(const short8*)kr;
        bk[g][1] = *(const short8*)(kr + 32);
    }
    const short8 ones = {0x3F80, 0x3F80, 0x3F80, 0x3F80, 0x3F80, 0x3F80, 0x3F80, 0x3F80};

    f32x4 accO[4][4];
    #pragma unroll
    for (int g = 0; g < 4; g++)
        #pragma unroll
        for (int dt = 0; dt < 4; dt++) accO[g][dt] = (f32x4){0.f, 0.f, 0.f, 0.f};
    f32x4 accL[4];
    #pragma unroll
    for (int g = 0; g < 4; g++) accL[g] = (f32x4){0.f, 0.f, 0.f, 0.f};

    const int srow = tid >> 2, seg = tid & 3;
    u16* sPw = sP + wave * 2 * 16 * QST;

    for (int s0 = 0; s0 < 2048; s0 += 64) {
        __syncthreads();
        {   // stage Q chunk [s][dk]
            const uint4* gq = (const uint4*)(Qbh + base + (size_t)(s0 + srow) * 64 + seg * 16);
            uint4 q0 = gq[0], q1 = gq[1];
            *(uint4*)&sQ[srow * QST + seg * 16]     = q0;
            *(uint4*)&sQ[srow * QST + seg * 16 + 8] = q1;
        }
        {   // stage V^T chunk [dk][s]
            const uint4* gv = (const uint4*)(Vtg + ((size_t)bh * 64 + srow) * 2048 + s0 + seg * 16);
            uint4 v0 = gv[0], v1 = gv[1];
            *(uint4*)&sVt[srow * QST + seg * 16]     = v0;
            *(uint4*)&sVt[srow * QST + seg * 16 + 8] = v1;
        }
        __syncthreads();

        short8 aq[4][2], av[2][4];
        #pragma unroll
        for (int nt = 0; nt < 4; nt++) {
            aq[nt][0] = *(const short8*)&sQ[(nt * 16 + l16) * QST + quad * 8];
            aq[nt][1] = *(const short8*)&sQ[(nt * 16 + l16) * QST + 32 + quad * 8];
        }
        #pragma unroll
        for (int kk = 0; kk < 2; kk++)
            #pragma unroll
            for (int dt = 0; dt < 4; dt++)
                av[kk][dt] = *(const short8*)&sVt[(dt * 16 + l16) * QST + kk * 32 + quad * 8];

        #pragma unroll
        for (int g = 0; g < 4; g++) {
            f32x4 aS[4];
            #pragma unroll
            for (int nt = 0; nt < 4; nt++) {
                f32x4 s = __builtin_amdgcn_mfma_f32_16x16x32_bf16(aq[nt][0], bk[g][0],
                            (f32x4){0.f, 0.f, 0.f, 0.f}, 0, 0, 0);
                aS[nt] = __builtin_amdgcn_mfma_f32_16x16x32_bf16(aq[nt][1], bk[g][1], s, 0, 0, 0);
            }
            u16* pb = sPw + (g & 1) * 16 * QST;
            #pragma unroll
            for (int nt = 0; nt < 4; nt++) {
                float p0 = __builtin_amdgcn_exp2f(aS[nt][0]);
                float p1 = __builtin_amdgcn_exp2f(aS[nt][1]);
                float p2 = __builtin_amdgcn_exp2f(aS[nt][2]);
                float p3 = __builtin_amdgcn_exp2f(aS[nt][3]);
                uint2 pk = { pack_trunc(p0, p1), pack_trunc(p2, p3) };
                *(uint2*)&pb[l16 * QST + nt * 16 + quad * 4] = pk;
            }
            #pragma unroll
            for (int kk = 0; kk < 2; kk++) {
                short8 bp = *(const short8*)&pb[l16 * QST + kk * 32 + quad * 8];
                accL[g] = __builtin_amdgcn_mfma_f32_16x16x32_bf16(ones, bp, accL[g], 0, 0, 0);
                #pragma unroll
                for (int dt = 0; dt < 4; dt++)
                    accO[g][dt] = __builtin_amdgcn_mfma_f32_16x16x32_bf16(av[kk][dt], bp, accO[g][dt], 0, 0, 0);
            }
        }
    }

    const int b = bh >> 4, h = bh & 15;
    #pragma unroll
    for (int g = 0; g < 4; g++) {
        float inv = 1.f / accL[g][0];
        int t = tw + g * 16 + l16;
        u16* orow = ctx + ((size_t)(b * 2048 + t)) * 1024 + h * 64;
        #pragma unroll
        for (int dt = 0; dt < 4; dt++) {
            union { u16 h4[4]; uint2 u; } o;
            #pragma unroll
            for (int r = 0; r < 4; r++) o.h4[r] = f2bf(accO[g][dt][r] * inv);
            *(uint2*)&orow[dt * 16 + quad * 4] = o.u;
        }
    }
}

// ---------------- launcher ----------------
extern "C" void kernel_launch(void* const* d_in, const int* in_sizes, int n_in,
                              void* d_out, int out_size, void* d_ws, size_t ws_size,
                              hipStream_t stream) {
    const float* keys    = (const float*)d_in[0];
    const float* queries = (const float*)d_in[1];
    const float* values  = (const float*)d_in[2];
    // d_in[3] = pad_mask (unused by the reference, faithfully ignored)
    const float* WKw = (const float*)d_in[4];
    const float* WKb = (const float*)d_in[5];
    const float* WQw = (const float*)d_in[6];
    const float* WQb = (const float*)d_in[7];
    const float* WVw = (const float*)d_in[8];
    const float* WVb = (const float*)d_in[9];
    const float* WOw = (const float*)d_in[10];
    const float* WOb = (const float*)d_in[11];

    char* ws = (char*)d_ws;
    const size_t MB = 1 << 20;
    u16* Kbh = (u16*)(ws + 0 * MB);    // [bh][t][64]   16MB
    u16* Qbh = (u16*)(ws + 16 * MB);   // [bh][s][64]   16MB
    u16* Vtg = (u16*)(ws + 32 * MB);   // [bh][64][t]   16MB
    u16* ctx = (u16*)(ws + 48 * MB);   // [b][t][h*64]  16MB

    const float kscale = 1.4426950408889634f * 0.125f;  // log2(e)/sqrt(d_key)
    gemm_qkv<<<1536, 256, 0, stream>>>(keys, queries, values, WKw, WQw, WVw,
                                       WKb, WQb, WVb, Kbh, Qbh, Vtg, kscale);

    attn_kernel<<<512, 256, 0, stream>>>(Kbh, Qbh, Vtg, ctx);

    gemm_out<<<1024, 256, 0, stream>>>(ctx, WOw, WOb, (float*)d_out);
}